// Round 11
// baseline (394.272 us; speedup 1.0000x reference)
//
#include <hip/hip_runtime.h>
#include <math.h>

#define NUM_GRAPHS 64
#define D 128
#define MT 64      // GEMM rows per block
#define ETILE 4096 // edges per partition block
#define NREP 16    // hg replicas for low-contention pooling atomics

typedef __attribute__((ext_vector_type(8))) short bf16x8;
typedef __attribute__((ext_vector_type(4))) float f32x4;
typedef __attribute__((ext_vector_type(2))) float f32x2;

__device__ __forceinline__ unsigned bf16rne(float x) {
    unsigned u = __float_as_uint(x);
    return (u + 0x7fffu + ((u >> 16) & 1u)) >> 16;
}
__device__ __forceinline__ float bflo(unsigned u) { return __uint_as_float(u << 16); }
__device__ __forceinline__ float bfhi(unsigned u) { return __uint_as_float(u & 0xffff0000u); }

// monotone float <-> uint order-preserving encoding (for atomicMax on float)
__device__ __forceinline__ unsigned encf(float f) {
    unsigned u = __float_as_uint(f);
    return (u & 0x80000000u) ? ~u : (u | 0x80000000u);
}
__device__ __forceinline__ float decf(unsigned e) {
    unsigned u = (e & 0x80000000u) ? (e & 0x7fffffffu) : ~e;
    return __uint_as_float(u);
}

// ---------------- front kernel: bucket hist + weight prep + graph bounds ----------------

__global__ __launch_bounds__(256) void k_front(
    const int* __restrict__ dst, int* __restrict__ bhist, int E, int nbT,
    const float* __restrict__ W1, const float* __restrict__ W2,
    unsigned short* __restrict__ Wt1, unsigned short* __restrict__ Wt2,
    const int* __restrict__ gid, int* __restrict__ gs, int* __restrict__ ge, int N) {
    __shared__ int h[1024];
    int b = blockIdx.x;
    int tid = threadIdx.x;
    if (b < nbT) {
        for (int i = tid; i < 1024; i += 256) h[i] = 0;
        __syncthreads();
        int e0 = b * ETILE;
        int e1 = min(e0 + ETILE, E);
        for (int i = e0 + tid; i < e1; i += 256) atomicAdd(&h[dst[i] >> 7], 1);
        __syncthreads();
        for (int i = tid; i < 1024; i += 256)
            if (h[i]) atomicAdd(&bhist[i], h[i]);
    } else if (b < nbT + 16) {
        // weight transpose role: Wt[n][k] packed bf16 (MFMA B-fragment layout)
        int bb = b - nbT;
        const float* W = (bb & 8) ? W2 : W1;
        unsigned short* Wt = (bb & 8) ? Wt2 : Wt1;
        int n = (bb & 7) * 16 + (tid >> 4);
        int c = tid & 15;
        unsigned v[8];
        #pragma unroll
        for (int j = 0; j < 8; ++j) v[j] = bf16rne(W[(c * 8 + j) * D + n]);
        uint4 pk;
        pk.x = v[0] | (v[1] << 16);
        pk.y = v[2] | (v[3] << 16);
        pk.z = v[4] | (v[5] << 16);
        pk.w = v[6] | (v[7] << 16);
        ((uint4*)Wt)[n * 16 + c] = pk;
    } else {
        int n = (b - nbT - 16) * 256 + tid;
        if (n >= N) return;
        int g = gid[n];
        if (n == 0 || gid[n - 1] != g) gs[g] = n;
        if (n == N - 1 || gid[n + 1] != g) ge[g] = n;
    }
}

__global__ __launch_bounds__(1024) void k_bucket_scan(const int* __restrict__ bhist,
                                                      int* __restrict__ bbase,
                                                      int* __restrict__ bcur,
                                                      int NB, int E,
                                                      int* __restrict__ row_ptr, int N,
                                                      const int* __restrict__ gs,
                                                      const int* __restrict__ ge,
                                                      float* __restrict__ ginv) {
    __shared__ int sm[1024];
    int t = threadIdx.x;
    int v = (t < NB) ? bhist[t] : 0;
    sm[t] = v;
    __syncthreads();
    for (int off = 1; off < 1024; off <<= 1) {
        int y = (t >= off) ? sm[t - off] : 0;
        __syncthreads();
        sm[t] += y;
        __syncthreads();
    }
    if (t < NB) { bbase[t] = sm[t] - v; bcur[t] = sm[t] - v; }
    if (t == 0) { bbase[NB] = E; row_ptr[N] = E; }
    if (t < NUM_GRAPHS) {
        int s = gs[t], e = ge[t];
        ginv[t] = (s <= e) ? 1.f / (float)(e - s + 1) : 0.f;
    }
}

__global__ __launch_bounds__(256) void k_partition(const int* __restrict__ src,
                                                   const int* __restrict__ dst,
                                                   int* __restrict__ bcur,
                                                   unsigned* __restrict__ part, int E) {
    __shared__ int h[1024];
    __shared__ int cur[1024];
    int tid = threadIdx.x;
    for (int i = tid; i < 1024; i += 256) h[i] = 0;
    __syncthreads();
    int e0 = blockIdx.x * ETILE;
    int e1 = min(e0 + ETILE, E);
    for (int i = e0 + tid; i < e1; i += 256) atomicAdd(&h[dst[i] >> 7], 1);
    __syncthreads();
    for (int i = tid; i < 1024; i += 256) {
        int c = h[i];
        cur[i] = c ? atomicAdd(&bcur[i], c) : 0;
    }
    __syncthreads();
    for (int i = e0 + tid; i < e1; i += 256) {
        int d = dst[i];
        int b = d >> 7;
        int pos = atomicAdd(&cur[b], 1);
        part[pos] = (unsigned)src[i] | ((unsigned)(d & 127) << 17);
    }
}

// ---------------- MFMA GEMM (+el/er + atomic global el-max) fused with bucket->CSR -----
// R7 structure restored: W staged in LDS (48 KB total). R9's direct-global B
// regressed ~30 us (B-fragment VGPR pressure serialized the MFMA stream).

__global__ __launch_bounds__(256) void k_gemm_mfma_sort(
    const void* __restrict__ Xv, int x_fp32,
    const unsigned short* __restrict__ Wt16,
    const float* __restrict__ al, const float* __restrict__ ar,
    unsigned short* __restrict__ feat16, float* __restrict__ el,
    float* __restrict__ er, unsigned* __restrict__ glmax_u, int N, int gemmBlocks,
    const unsigned* __restrict__ part, const int* __restrict__ bbase,
    int* __restrict__ row_ptr, int* __restrict__ csr_src) {
    __shared__ uint4 WsU[128 * 16];  // 32 KB
    __shared__ uint4 XsU[MT * 16];   // 16 KB
    __shared__ float smax[4];
    int bx = blockIdx.x;
    int T = gridDim.x;
    int g0 = (int)((long long)bx * gemmBlocks / T);
    int g1 = (int)((long long)(bx + 1) * gemmBlocks / T);
    int tid = threadIdx.x;

    if (g1 == g0) {
        // ---- sort role: bucket -> CSR ----
        int b = bx - g0;
        int base = bbase[b];
        int bcnt = bbase[b + 1] - base;
        int* ldeg = (int*)XsU;
        int* lcur = ldeg + 128;
        if (tid < 128) ldeg[tid] = 0;
        __syncthreads();
        for (int i = tid; i < bcnt; i += 256)
            atomicAdd(&ldeg[part[base + i] >> 17], 1);
        __syncthreads();
        int myv = (tid < 128) ? ldeg[tid] : 0;
        for (int off = 1; off < 128; off <<= 1) {
            int y = 0;
            if (tid < 128 && tid >= off) y = ldeg[tid - off];
            __syncthreads();
            if (tid < 128) ldeg[tid] += y;
            __syncthreads();
        }
        if (tid < 128) {
            int excl = ldeg[tid] - myv;
            int node = (b << 7) + tid;
            if (node < N) row_ptr[node] = base + excl;
            lcur[tid] = base + excl;
        }
        __syncthreads();
        for (int i = tid; i < bcnt; i += 256) {
            unsigned v = part[base + i];
            int pos = atomicAdd(&lcur[v >> 17], 1);
            csr_src[pos] = (int)(v & 0x1FFFFu);
        }
        return;
    }

    // ---- gemm role ----
    int row0 = g0 * MT;

    for (int idx = tid; idx < 128 * 16; idx += 256) {
        int n = idx >> 4, c = idx & 15;
        WsU[(n << 4) | (c ^ (n & 15))] = ((const uint4*)Wt16)[idx];
    }
    if (x_fp32) {
        const float4* X4 = (const float4*)Xv;
        for (int idx = tid; idx < MT * 16; idx += 256) {
            int n = idx >> 4, c = idx & 15;
            int row = row0 + n;
            uint4 o = make_uint4(0, 0, 0, 0);
            if (row < N) {
                float4 f0 = X4[(size_t)row * 32 + c * 2];
                float4 f1 = X4[(size_t)row * 32 + c * 2 + 1];
                o.x = bf16rne(f0.x) | (bf16rne(f0.y) << 16);
                o.y = bf16rne(f0.z) | (bf16rne(f0.w) << 16);
                o.z = bf16rne(f1.x) | (bf16rne(f1.y) << 16);
                o.w = bf16rne(f1.z) | (bf16rne(f1.w) << 16);
            }
            XsU[(n << 4) | (c ^ (n & 15))] = o;
        }
    } else {
        const uint4* X16 = (const uint4*)Xv;
        for (int idx = tid; idx < MT * 16; idx += 256) {
            int n = idx >> 4, c = idx & 15;
            int row = row0 + n;
            uint4 o = make_uint4(0, 0, 0, 0);
            if (row < N) o = X16[(size_t)row * 16 + c];
            XsU[(n << 4) | (c ^ (n & 15))] = o;
        }
    }
    __syncthreads();

    int lane = tid & 63, w = tid >> 6;
    int quad = lane >> 4, l16 = lane & 15;
    const bf16x8* WsF = (const bf16x8*)WsU;
    const bf16x8* XsF = (const bf16x8*)XsU;
    f32x4 acc[8];
    #pragma unroll
    for (int i = 0; i < 8; ++i) acc[i] = (f32x4){0.f, 0.f, 0.f, 0.f};

    int arow = w * 16 + l16;
    #pragma unroll
    for (int ks = 0; ks < 4; ++ks) {
        int c = ks * 4 + quad;
        bf16x8 A = XsF[(arow << 4) | (c ^ l16)];
        #pragma unroll
        for (int nt = 0; nt < 8; ++nt) {
            bf16x8 B = WsF[((nt * 16 + l16) << 4) | (c ^ l16)];
            acc[nt] = __builtin_amdgcn_mfma_f32_16x16x32_bf16(A, B, acc[nt], 0, 0, 0);
        }
    }

    // el/er epilogue + block el-max
    float alv[8], arv[8];
    #pragma unroll
    for (int nt = 0; nt < 8; ++nt) { alv[nt] = al[nt * 16 + l16]; arv[nt] = ar[nt * 16 + l16]; }
    float lmax = -1e30f;
    #pragma unroll
    for (int r = 0; r < 4; ++r) {
        float pl = 0.f, pr = 0.f;
        #pragma unroll
        for (int nt = 0; nt < 8; ++nt) { pl += acc[nt][r] * alv[nt]; pr += acc[nt][r] * arv[nt]; }
        #pragma unroll
        for (int o = 1; o < 16; o <<= 1) { pl += __shfl_xor(pl, o); pr += __shfl_xor(pr, o); }
        int row = row0 + w * 16 + quad * 4 + r;
        if (l16 == 0 && row < N) { el[row] = pl; er[row] = pr; }
        lmax = fmaxf(lmax, pl);
    }
    lmax = fmaxf(lmax, __shfl_xor(lmax, 16));
    lmax = fmaxf(lmax, __shfl_xor(lmax, 32));
    if (lane == 0) smax[w] = lmax;

    unsigned short* XsS = (unsigned short*)XsU;
    #pragma unroll
    for (int nt = 0; nt < 8; ++nt)
        #pragma unroll
        for (int r = 0; r < 4; ++r) {
            int lrow = w * 16 + quad * 4 + r;
            int col = nt * 16 + l16;
            int ch = col >> 3;
            int sc = ch ^ (lrow & 15);
            XsS[lrow * 128 + sc * 8 + (col & 7)] = (unsigned short)bf16rne(acc[nt][r]);
        }
    __syncthreads();
    if (tid == 0) {
        float bm = fmaxf(fmaxf(smax[0], smax[1]), fmaxf(smax[2], smax[3]));
        atomicMax(glmax_u, encf(bm));
    }
    for (int idx = tid; idx < MT * 16; idx += 256) {
        int n = idx >> 4, c = idx & 15;
        int row = row0 + n;
        if (row < N) ((uint4*)feat16)[(size_t)row * 16 + c] = XsU[(n << 4) | (c ^ (n & 15))];
    }
}

// ---------------- single-pass edge-softmax + aggregation (global-max shift) --------
// POOL=false (layer 1): write bf16 features. POOL=true (layer 2): fuse mean-
// pooling -- scale by 1/cnt, LDS-combine the block's 4 nodes (sorted gid =>
// graph runs), run-length atomicAdd into one of NREP hg replicas.

template <bool POOL>
__global__ __launch_bounds__(256) void k_aggregate(
    const unsigned short* __restrict__ feat16, const float* __restrict__ el,
    const float* __restrict__ er, const int* __restrict__ row_ptr,
    const int* __restrict__ csr_src, const float* __restrict__ bias,
    const unsigned* __restrict__ glmax_u, unsigned short* __restrict__ outv,
    const int* __restrict__ gid, const float* __restrict__ ginv,
    float* __restrict__ hgrep, int N) {
    int tid = threadIdx.x;
    int wid = (blockIdx.x * blockDim.x + tid) >> 6;
    int lane = tid & 63;
    int w = tid >> 6;
    bool active = wid < N;
    if (!POOL && !active) return;

    float v[8];
    int g = 0;
    float ic = 0.f;
    if (active) {
        int beg = row_ptr[wid], end = row_ptr[wid + 1];
        float erd = er[wid];
        float M = decf(glmax_u[0]) + erd;
        M = fmaxf(M, 0.2f * M);

        int qa = lane >> 4, sub = lane & 15;
        const char* fb = (const char*)feat16 + (sub << 4);
        f32x2 a0 = {0.f, 0.f}, a1 = {0.f, 0.f}, a2 = {0.f, 0.f}, a3 = {0.f, 0.f};
        float s = 0.f;
        int j = beg + qa;
        for (; j + 12 < end; j += 16) {
            int sn0 = csr_src[j], sn1 = csr_src[j + 4];
            int sn2 = csr_src[j + 8], sn3 = csr_src[j + 12];
            float t0 = el[sn0] + erd, t1 = el[sn1] + erd;
            float t2 = el[sn2] + erd, t3 = el[sn3] + erd;
            uint4 q0 = *(const uint4*)(fb + ((unsigned)sn0 << 8));
            uint4 q1 = *(const uint4*)(fb + ((unsigned)sn1 << 8));
            uint4 q2 = *(const uint4*)(fb + ((unsigned)sn2 << 8));
            uint4 q3 = *(const uint4*)(fb + ((unsigned)sn3 << 8));
            t0 = fmaxf(t0, 0.2f * t0); t1 = fmaxf(t1, 0.2f * t1);
            t2 = fmaxf(t2, 0.2f * t2); t3 = fmaxf(t3, 0.2f * t3);
            float w0 = __expf(t0 - M), w1 = __expf(t1 - M);
            float w2 = __expf(t2 - M), w3 = __expf(t3 - M);
            s += (w0 + w1) + (w2 + w3);
            f32x2 f;
            f.x = bflo(q0.x); f.y = bfhi(q0.x); a0 += w0 * f;
            f.x = bflo(q0.y); f.y = bfhi(q0.y); a1 += w0 * f;
            f.x = bflo(q0.z); f.y = bfhi(q0.z); a2 += w0 * f;
            f.x = bflo(q0.w); f.y = bfhi(q0.w); a3 += w0 * f;
            f.x = bflo(q1.x); f.y = bfhi(q1.x); a0 += w1 * f;
            f.x = bflo(q1.y); f.y = bfhi(q1.y); a1 += w1 * f;
            f.x = bflo(q1.z); f.y = bfhi(q1.z); a2 += w1 * f;
            f.x = bflo(q1.w); f.y = bfhi(q1.w); a3 += w1 * f;
            f.x = bflo(q2.x); f.y = bfhi(q2.x); a0 += w2 * f;
            f.x = bflo(q2.y); f.y = bfhi(q2.y); a1 += w2 * f;
            f.x = bflo(q2.z); f.y = bfhi(q2.z); a2 += w2 * f;
            f.x = bflo(q2.w); f.y = bfhi(q2.w); a3 += w2 * f;
            f.x = bflo(q3.x); f.y = bfhi(q3.x); a0 += w3 * f;
            f.x = bflo(q3.y); f.y = bfhi(q3.y); a1 += w3 * f;
            f.x = bflo(q3.z); f.y = bfhi(q3.z); a2 += w3 * f;
            f.x = bflo(q3.w); f.y = bfhi(q3.w); a3 += w3 * f;
        }
        for (; j + 4 < end; j += 8) {
            int sn0 = csr_src[j], sn1 = csr_src[j + 4];
            float t0 = el[sn0] + erd, t1 = el[sn1] + erd;
            uint4 q0 = *(const uint4*)(fb + ((unsigned)sn0 << 8));
            uint4 q1 = *(const uint4*)(fb + ((unsigned)sn1 << 8));
            t0 = fmaxf(t0, 0.2f * t0); t1 = fmaxf(t1, 0.2f * t1);
            float w0 = __expf(t0 - M), w1 = __expf(t1 - M);
            s += w0 + w1;
            f32x2 f;
            f.x = bflo(q0.x); f.y = bfhi(q0.x); a0 += w0 * f;
            f.x = bflo(q0.y); f.y = bfhi(q0.y); a1 += w0 * f;
            f.x = bflo(q0.z); f.y = bfhi(q0.z); a2 += w0 * f;
            f.x = bflo(q0.w); f.y = bfhi(q0.w); a3 += w0 * f;
            f.x = bflo(q1.x); f.y = bfhi(q1.x); a0 += w1 * f;
            f.x = bflo(q1.y); f.y = bfhi(q1.y); a1 += w1 * f;
            f.x = bflo(q1.z); f.y = bfhi(q1.z); a2 += w1 * f;
            f.x = bflo(q1.w); f.y = bfhi(q1.w); a3 += w1 * f;
        }
        if (j < end) {
            int sn = csr_src[j];
            float t = el[sn] + erd;
            uint4 q = *(const uint4*)(fb + ((unsigned)sn << 8));
            t = fmaxf(t, 0.2f * t);
            float wq = __expf(t - M);
            s += wq;
            f32x2 f;
            f.x = bflo(q.x); f.y = bfhi(q.x); a0 += wq * f;
            f.x = bflo(q.y); f.y = bfhi(q.y); a1 += wq * f;
            f.x = bflo(q.z); f.y = bfhi(q.z); a2 += wq * f;
            f.x = bflo(q.w); f.y = bfhi(q.w); a3 += wq * f;
        }
        float vr[8] = {a0.x, a0.y, a1.x, a1.y, a2.x, a2.y, a3.x, a3.y};
        #pragma unroll
        for (int c = 0; c < 8; ++c) {
            vr[c] += __shfl_xor(vr[c], 16);
            vr[c] += __shfl_xor(vr[c], 32);
        }
        s += __shfl_xor(s, 16);
        s += __shfl_xor(s, 32);
        float inv = (end > beg) ? 1.f / s : 0.f;
        if (lane < 16) {
            float4 b0 = ((const float4*)bias)[lane * 2];
            float4 b1 = ((const float4*)bias)[lane * 2 + 1];
            v[0] = fmaxf(vr[0] * inv + b0.x, 0.f);
            v[1] = fmaxf(vr[1] * inv + b0.y, 0.f);
            v[2] = fmaxf(vr[2] * inv + b0.z, 0.f);
            v[3] = fmaxf(vr[3] * inv + b0.w, 0.f);
            v[4] = fmaxf(vr[4] * inv + b1.x, 0.f);
            v[5] = fmaxf(vr[5] * inv + b1.y, 0.f);
            v[6] = fmaxf(vr[6] * inv + b1.z, 0.f);
            v[7] = fmaxf(vr[7] * inv + b1.w, 0.f);
        }
        if (POOL) { g = gid[wid]; ic = ginv[g]; }
    }

    if (POOL) {
        __shared__ float smp[4][128];
        __shared__ int sgr[4];
        if (lane < 16) {
            #pragma unroll
            for (int k = 0; k < 8; ++k)
                smp[w][lane * 8 + k] = active ? v[k] * ic : 0.f;
        }
        if (lane == 0) sgr[w] = active ? g : -1;
        __syncthreads();
        if (tid < 128) {
            int rep = (int)(blockIdx.x & (NREP - 1));
            float* hb = hgrep + (size_t)rep * NUM_GRAPHS * D + tid;
            int gprev = -1; float sacc = 0.f;
            #pragma unroll
            for (int ww = 0; ww < 4; ++ww) {
                int gg = sgr[ww];
                if (gg < 0) continue;
                float val = smp[ww][tid];
                if (gg == gprev) sacc += val;
                else {
                    if (gprev >= 0) atomicAdd(hb + gprev * D, sacc);
                    gprev = gg; sacc = val;
                }
            }
            if (gprev >= 0) atomicAdd(hb + gprev * D, sacc);
        }
    } else {
        if (lane < 16) {
            uint4 pk;
            pk.x = bf16rne(v[0]) | (bf16rne(v[1]) << 16);
            pk.y = bf16rne(v[2]) | (bf16rne(v[3]) << 16);
            pk.z = bf16rne(v[4]) | (bf16rne(v[5]) << 16);
            pk.w = bf16rne(v[6]) | (bf16rne(v[7]) << 16);
            ((uint4*)outv)[(size_t)wid * 16 + lane] = pk;
        }
    }
}

// ---------------- final: fold hg replicas + FC + log_softmax ----------------

__global__ __launch_bounds__(256) void k_final(const float* __restrict__ hgrep,
                                               const float* __restrict__ Wfc,
                                               const float* __restrict__ bfc,
                                               float* __restrict__ out) {
    __shared__ float hgs[NUM_GRAPHS * D];   // 32 KB
    int tid = threadIdx.x;
    for (int i = tid; i < NUM_GRAPHS * D; i += 256) {
        float v = 0.f;
        #pragma unroll
        for (int r = 0; r < NREP; ++r) v += hgrep[(size_t)r * NUM_GRAPHS * D + i];
        hgs[i] = v;
    }
    __syncthreads();
    if (tid < NUM_GRAPHS) {
        float l0 = bfc[0], l1 = bfc[1];
        for (int d = 0; d < D; d++) {
            float v = hgs[tid * D + d];
            l0 += v * Wfc[2 * d];
            l1 += v * Wfc[2 * d + 1];
        }
        float mm = fmaxf(l0, l1);
        float lse = mm + logf(expf(l0 - mm) + expf(l1 - mm));
        out[2 * tid] = l0 - lse;
        out[2 * tid + 1] = l1 - lse;
    }
}

// ---------------- launch ----------------

extern "C" void kernel_launch(void* const* d_in, const int* in_sizes, int n_in,
                              void* d_out, int out_size, void* d_ws, size_t ws_size,
                              hipStream_t stream) {
    const float* h   = (const float*)d_in[0];
    const int* src   = (const int*)d_in[1];
    const int* dst   = (const int*)d_in[2];
    const int* gid   = (const int*)d_in[3];
    const float* W1  = (const float*)d_in[4];
    const float* al1 = (const float*)d_in[5];
    const float* ar1 = (const float*)d_in[6];
    const float* b1  = (const float*)d_in[7];
    const float* W2  = (const float*)d_in[8];
    const float* al2 = (const float*)d_in[9];
    const float* ar2 = (const float*)d_in[10];
    const float* b2  = (const float*)d_in[11];
    const float* Wfc = (const float*)d_in[12];
    const float* bfc = (const float*)d_in[13];
    float* out = (float*)d_out;

    int N = in_sizes[0] / D;
    int E = in_sizes[1];
    int NB = (N + 127) >> 7;

    char* p = (char*)d_ws;
    unsigned short* feat16  = (unsigned short*)p; p += (size_t)N * D * 2;  // GEMM out
    unsigned short* featAgg = (unsigned short*)p; p += (size_t)N * D * 2;  // agg1 out (bf16)
    float* el    = (float*)p; p += (size_t)N * 4;
    float* er    = (float*)p; p += (size_t)N * 4;
    int* row_ptr = (int*)p;   p += (size_t)(N + 4) * 4;
    int* csr_src = (int*)p;   p += (size_t)E * 4;
    unsigned* part = (unsigned*)p; p += (size_t)E * 4;
    // zero-region: bhist + glmax + hgrep (one memset)
    int* bhist   = (int*)p;   p += 1028 * 4;
    unsigned* glmaxu = (unsigned*)p; p += 4 * 4;
    float* hgrep = (float*)p; p += (size_t)NREP * NUM_GRAPHS * D * 4;
    size_t zbytes = (char*)p - (char*)bhist;
    int* bbase   = (int*)p;   p += 1028 * 4;
    int* bcur    = (int*)p;   p += 1028 * 4;
    int* gs      = (int*)p;   p += NUM_GRAPHS * 4;
    int* ge      = (int*)p;   p += NUM_GRAPHS * 4;
    float* ginv  = (float*)p; p += NUM_GRAPHS * 4;
    unsigned short* Wt1 = (unsigned short*)p; p += D * D * 2;
    unsigned short* Wt2 = (unsigned short*)p; p += D * D * 2;

    int nbN = (N + 255) / 256;
    int nbW = (N * 64 + 255) / 256;
    int nbT = (E + ETILE - 1) / ETILE;
    int gemmB = (N + MT - 1) / MT;

    hipMemsetAsync(bhist, 0, zbytes, stream);                // bhist + glmax + hgrep
    hipMemsetAsync(gs, 0x7f, NUM_GRAPHS * 4, stream);
    hipMemsetAsync(ge, 0xff, NUM_GRAPHS * 4, stream);

    // front: bucket histogram + weight transpose + graph bounds (one kernel)
    k_front<<<nbT + 16 + nbN, 256, 0, stream>>>(dst, bhist, E, nbT,
                                                W1, W2, Wt1, Wt2, gid, gs, ge, N);
    k_bucket_scan<<<1, 1024, 0, stream>>>(bhist, bbase, bcur, NB, E, row_ptr, N,
                                          gs, ge, ginv);
    k_partition<<<nbT, 256, 0, stream>>>(src, dst, bcur, part, E);

    // Layer 1: MFMA GEMM (fp32 in) + el/er + glmax, overlapped with bucket->CSR
    k_gemm_mfma_sort<<<gemmB + NB, 256, 0, stream>>>(
        h, 1, Wt1, al1, ar1, feat16, el, er, glmaxu, N, gemmB,
        part, bbase, row_ptr, csr_src);
    k_aggregate<false><<<nbW, 256, 0, stream>>>(feat16, el, er, row_ptr, csr_src,
                                                b1, glmaxu, featAgg,
                                                gid, ginv, hgrep, N);

    // Layer 2: MFMA GEMM (bf16 in) + fused pooling aggregate
    k_gemm_mfma_sort<<<gemmB, 256, 0, stream>>>(
        featAgg, 0, Wt2, al2, ar2, feat16, el, er, glmaxu + 1, N, gemmB,
        part, bbase, row_ptr, csr_src);
    k_aggregate<true><<<nbW, 256, 0, stream>>>(feat16, el, er, row_ptr, csr_src,
                                               b2, glmaxu + 1, (unsigned short*)0,
                                               gid, ginv, hgrep, N);

    // FC + log_softmax
    k_final<<<1, 256, 0, stream>>>(hgrep, Wfc, bfc, out);
}

// Round 12
// 359.194 us; speedup vs baseline: 1.0977x; 1.0977x over previous
//
#include <hip/hip_runtime.h>
#include <math.h>

#define NUM_GRAPHS 64
#define D 128
#define PCHUNK 16
#define MT 64      // GEMM rows per block
#define ETILE 8192 // edges per partition block (R11: 2x fewer hist-merge atomics)

typedef __attribute__((ext_vector_type(8))) short bf16x8;
typedef __attribute__((ext_vector_type(4))) float f32x4;
typedef __attribute__((ext_vector_type(2))) float f32x2;

__device__ __forceinline__ unsigned bf16rne(float x) {
    unsigned u = __float_as_uint(x);
    return (u + 0x7fffu + ((u >> 16) & 1u)) >> 16;
}
__device__ __forceinline__ float bflo(unsigned u) { return __uint_as_float(u << 16); }
__device__ __forceinline__ float bfhi(unsigned u) { return __uint_as_float(u & 0xffff0000u); }

// monotone float <-> uint order-preserving encoding (for atomicMax on float)
__device__ __forceinline__ unsigned encf(float f) {
    unsigned u = __float_as_uint(f);
    return (u & 0x80000000u) ? ~u : (u | 0x80000000u);
}
__device__ __forceinline__ float decf(unsigned e) {
    unsigned u = (e & 0x80000000u) ? (e & 0x7fffffffu) : ~e;
    return __uint_as_float(u);
}

// ---------------- front kernel: bucket hist + weight prep + graph bounds ----------------

__global__ __launch_bounds__(256) void k_front(
    const int* __restrict__ dst, int* __restrict__ bhist, int E, int nbT,
    const float* __restrict__ W1, const float* __restrict__ W2,
    unsigned short* __restrict__ Wt1, unsigned short* __restrict__ Wt2,
    const int* __restrict__ gid, int* __restrict__ gs, int* __restrict__ ge, int N) {
    __shared__ int h[1024];
    int b = blockIdx.x;
    int tid = threadIdx.x;
    if (b < nbT) {
        for (int i = tid; i < 1024; i += 256) h[i] = 0;
        __syncthreads();
        int e0 = b * ETILE;
        int e1 = min(e0 + ETILE, E);
        for (int i = e0 + tid; i < e1; i += 256) atomicAdd(&h[dst[i] >> 7], 1);
        __syncthreads();
        for (int i = tid; i < 1024; i += 256)
            if (h[i]) atomicAdd(&bhist[i], h[i]);
    } else if (b < nbT + 16) {
        // weight transpose role: Wt[n][k] packed bf16 (MFMA B-fragment layout)
        int bb = b - nbT;
        const float* W = (bb & 8) ? W2 : W1;
        unsigned short* Wt = (bb & 8) ? Wt2 : Wt1;
        int n = (bb & 7) * 16 + (tid >> 4);
        int c = tid & 15;
        unsigned v[8];
        #pragma unroll
        for (int j = 0; j < 8; ++j) v[j] = bf16rne(W[(c * 8 + j) * D + n]);
        uint4 pk;
        pk.x = v[0] | (v[1] << 16);
        pk.y = v[2] | (v[3] << 16);
        pk.z = v[4] | (v[5] << 16);
        pk.w = v[6] | (v[7] << 16);
        ((uint4*)Wt)[n * 16 + c] = pk;
    } else {
        int n = (b - nbT - 16) * 256 + tid;
        if (n >= N) return;
        int g = gid[n];
        if (n == 0 || gid[n - 1] != g) gs[g] = n;
        if (n == N - 1 || gid[n + 1] != g) ge[g] = n;
    }
}

__global__ __launch_bounds__(1024) void k_bucket_scan(const int* __restrict__ bhist,
                                                      int* __restrict__ bbase,
                                                      int* __restrict__ bcur,
                                                      int NB, int E,
                                                      int* __restrict__ row_ptr, int N) {
    __shared__ int sm[1024];
    int t = threadIdx.x;
    int v = (t < NB) ? bhist[t] : 0;
    sm[t] = v;
    __syncthreads();
    for (int off = 1; off < 1024; off <<= 1) {
        int y = (t >= off) ? sm[t - off] : 0;
        __syncthreads();
        sm[t] += y;
        __syncthreads();
    }
    if (t < NB) { bbase[t] = sm[t] - v; bcur[t] = sm[t] - v; }
    if (t == 0) { bbase[NB] = E; row_ptr[N] = E; }
}

__global__ __launch_bounds__(256) void k_partition(const int* __restrict__ src,
                                                   const int* __restrict__ dst,
                                                   int* __restrict__ bcur,
                                                   unsigned* __restrict__ part, int E) {
    __shared__ int h[1024];
    __shared__ int cur[1024];
    int tid = threadIdx.x;
    for (int i = tid; i < 1024; i += 256) h[i] = 0;
    __syncthreads();
    int e0 = blockIdx.x * ETILE;
    int e1 = min(e0 + ETILE, E);
    for (int i = e0 + tid; i < e1; i += 256) atomicAdd(&h[dst[i] >> 7], 1);
    __syncthreads();
    for (int i = tid; i < 1024; i += 256) {
        int c = h[i];
        cur[i] = c ? atomicAdd(&bcur[i], c) : 0;
    }
    __syncthreads();
    for (int i = e0 + tid; i < e1; i += 256) {
        int d = dst[i];
        int b = d >> 7;
        int pos = atomicAdd(&cur[b], 1);
        part[pos] = (unsigned)src[i] | ((unsigned)(d & 127) << 17);
    }
}

// ---------------- MFMA GEMM (+el/er + atomic global el-max) fused with bucket->CSR -----
// R7 structure: W staged in LDS (48 KB total). Probed alternatives all worse:
// W-from-global (R9, +30us), split weights pass (R8, +37us), fused pool (R10, +38us).

__global__ __launch_bounds__(256) void k_gemm_mfma_sort(
    const void* __restrict__ Xv, int x_fp32,
    const unsigned short* __restrict__ Wt16,
    const float* __restrict__ al, const float* __restrict__ ar,
    unsigned short* __restrict__ feat16, float* __restrict__ el,
    float* __restrict__ er, unsigned* __restrict__ glmax_u, int N, int gemmBlocks,
    const unsigned* __restrict__ part, const int* __restrict__ bbase,
    int* __restrict__ row_ptr, int* __restrict__ csr_src) {
    __shared__ uint4 WsU[128 * 16];  // 32 KB
    __shared__ uint4 XsU[MT * 16];   // 16 KB
    __shared__ float smax[4];
    int bx = blockIdx.x;
    int T = gridDim.x;
    int g0 = (int)((long long)bx * gemmBlocks / T);
    int g1 = (int)((long long)(bx + 1) * gemmBlocks / T);
    int tid = threadIdx.x;

    if (g1 == g0) {
        // ---- sort role: bucket -> CSR ----
        int b = bx - g0;
        int base = bbase[b];
        int bcnt = bbase[b + 1] - base;
        int* ldeg = (int*)XsU;
        int* lcur = ldeg + 128;
        if (tid < 128) ldeg[tid] = 0;
        __syncthreads();
        for (int i = tid; i < bcnt; i += 256)
            atomicAdd(&ldeg[part[base + i] >> 17], 1);
        __syncthreads();
        int myv = (tid < 128) ? ldeg[tid] : 0;
        for (int off = 1; off < 128; off <<= 1) {
            int y = 0;
            if (tid < 128 && tid >= off) y = ldeg[tid - off];
            __syncthreads();
            if (tid < 128) ldeg[tid] += y;
            __syncthreads();
        }
        if (tid < 128) {
            int excl = ldeg[tid] - myv;
            int node = (b << 7) + tid;
            if (node < N) row_ptr[node] = base + excl;
            lcur[tid] = base + excl;
        }
        __syncthreads();
        for (int i = tid; i < bcnt; i += 256) {
            unsigned v = part[base + i];
            int pos = atomicAdd(&lcur[v >> 17], 1);
            csr_src[pos] = (int)(v & 0x1FFFFu);
        }
        return;
    }

    // ---- gemm role ----
    int row0 = g0 * MT;

    for (int idx = tid; idx < 128 * 16; idx += 256) {
        int n = idx >> 4, c = idx & 15;
        WsU[(n << 4) | (c ^ (n & 15))] = ((const uint4*)Wt16)[idx];
    }
    if (x_fp32) {
        const float4* X4 = (const float4*)Xv;
        for (int idx = tid; idx < MT * 16; idx += 256) {
            int n = idx >> 4, c = idx & 15;
            int row = row0 + n;
            uint4 o = make_uint4(0, 0, 0, 0);
            if (row < N) {
                float4 f0 = X4[(size_t)row * 32 + c * 2];
                float4 f1 = X4[(size_t)row * 32 + c * 2 + 1];
                o.x = bf16rne(f0.x) | (bf16rne(f0.y) << 16);
                o.y = bf16rne(f0.z) | (bf16rne(f0.w) << 16);
                o.z = bf16rne(f1.x) | (bf16rne(f1.y) << 16);
                o.w = bf16rne(f1.z) | (bf16rne(f1.w) << 16);
            }
            XsU[(n << 4) | (c ^ (n & 15))] = o;
        }
    } else {
        const uint4* X16 = (const uint4*)Xv;
        for (int idx = tid; idx < MT * 16; idx += 256) {
            int n = idx >> 4, c = idx & 15;
            int row = row0 + n;
            uint4 o = make_uint4(0, 0, 0, 0);
            if (row < N) o = X16[(size_t)row * 16 + c];
            XsU[(n << 4) | (c ^ (n & 15))] = o;
        }
    }
    __syncthreads();

    int lane = tid & 63, w = tid >> 6;
    int quad = lane >> 4, l16 = lane & 15;
    const bf16x8* WsF = (const bf16x8*)WsU;
    const bf16x8* XsF = (const bf16x8*)XsU;
    f32x4 acc[8];
    #pragma unroll
    for (int i = 0; i < 8; ++i) acc[i] = (f32x4){0.f, 0.f, 0.f, 0.f};

    int arow = w * 16 + l16;
    #pragma unroll
    for (int ks = 0; ks < 4; ++ks) {
        int c = ks * 4 + quad;
        bf16x8 A = XsF[(arow << 4) | (c ^ l16)];
        #pragma unroll
        for (int nt = 0; nt < 8; ++nt) {
            bf16x8 B = WsF[((nt * 16 + l16) << 4) | (c ^ l16)];
            acc[nt] = __builtin_amdgcn_mfma_f32_16x16x32_bf16(A, B, acc[nt], 0, 0, 0);
        }
    }

    // el/er epilogue + block el-max
    float alv[8], arv[8];
    #pragma unroll
    for (int nt = 0; nt < 8; ++nt) { alv[nt] = al[nt * 16 + l16]; arv[nt] = ar[nt * 16 + l16]; }
    float lmax = -1e30f;
    #pragma unroll
    for (int r = 0; r < 4; ++r) {
        float pl = 0.f, pr = 0.f;
        #pragma unroll
        for (int nt = 0; nt < 8; ++nt) { pl += acc[nt][r] * alv[nt]; pr += acc[nt][r] * arv[nt]; }
        #pragma unroll
        for (int o = 1; o < 16; o <<= 1) { pl += __shfl_xor(pl, o); pr += __shfl_xor(pr, o); }
        int row = row0 + w * 16 + quad * 4 + r;
        if (l16 == 0 && row < N) { el[row] = pl; er[row] = pr; }
        lmax = fmaxf(lmax, pl);
    }
    lmax = fmaxf(lmax, __shfl_xor(lmax, 16));
    lmax = fmaxf(lmax, __shfl_xor(lmax, 32));
    if (lane == 0) smax[w] = lmax;

    unsigned short* XsS = (unsigned short*)XsU;
    #pragma unroll
    for (int nt = 0; nt < 8; ++nt)
        #pragma unroll
        for (int r = 0; r < 4; ++r) {
            int lrow = w * 16 + quad * 4 + r;
            int col = nt * 16 + l16;
            int ch = col >> 3;
            int sc = ch ^ (lrow & 15);
            XsS[lrow * 128 + sc * 8 + (col & 7)] = (unsigned short)bf16rne(acc[nt][r]);
        }
    __syncthreads();
    if (tid == 0) {
        float bm = fmaxf(fmaxf(smax[0], smax[1]), fmaxf(smax[2], smax[3]));
        atomicMax(glmax_u, encf(bm));
    }
    for (int idx = tid; idx < MT * 16; idx += 256) {
        int n = idx >> 4, c = idx & 15;
        int row = row0 + n;
        if (row < N) ((uint4*)feat16)[(size_t)row * 16 + c] = XsU[(n << 4) | (c ^ (n & 15))];
    }
}

// ---------------- single-pass edge-softmax + aggregation (global-max shift) --------
// Gather-service-rate bound (R7/R8 A/B: dur invariant to VALU content). No
// barrier, no extra passes -- the probed optimum.

__global__ __launch_bounds__(256) void k_aggregate(
    const unsigned short* __restrict__ feat16, const float* __restrict__ el,
    const float* __restrict__ er, const int* __restrict__ row_ptr,
    const int* __restrict__ csr_src, const float* __restrict__ bias,
    const unsigned* __restrict__ glmax_u, unsigned short* __restrict__ outv, int N) {
    int wid = (blockIdx.x * blockDim.x + threadIdx.x) >> 6;
    int lane = threadIdx.x & 63;
    if (wid >= N) return;
    int beg = row_ptr[wid], end = row_ptr[wid + 1];
    float erd = er[wid];
    float M = decf(glmax_u[0]) + erd;
    M = fmaxf(M, 0.2f * M);

    int qa = lane >> 4, sub = lane & 15;
    const char* fb = (const char*)feat16 + (sub << 4);
    f32x2 a0 = {0.f, 0.f}, a1 = {0.f, 0.f}, a2 = {0.f, 0.f}, a3 = {0.f, 0.f};
    float s = 0.f;
    int j = beg + qa;
    for (; j + 12 < end; j += 16) {
        int sn0 = csr_src[j], sn1 = csr_src[j + 4];
        int sn2 = csr_src[j + 8], sn3 = csr_src[j + 12];
        float t0 = el[sn0] + erd, t1 = el[sn1] + erd;
        float t2 = el[sn2] + erd, t3 = el[sn3] + erd;
        uint4 q0 = *(const uint4*)(fb + ((unsigned)sn0 << 8));
        uint4 q1 = *(const uint4*)(fb + ((unsigned)sn1 << 8));
        uint4 q2 = *(const uint4*)(fb + ((unsigned)sn2 << 8));
        uint4 q3 = *(const uint4*)(fb + ((unsigned)sn3 << 8));
        t0 = fmaxf(t0, 0.2f * t0); t1 = fmaxf(t1, 0.2f * t1);
        t2 = fmaxf(t2, 0.2f * t2); t3 = fmaxf(t3, 0.2f * t3);
        float w0 = __expf(t0 - M), w1 = __expf(t1 - M);
        float w2 = __expf(t2 - M), w3 = __expf(t3 - M);
        s += (w0 + w1) + (w2 + w3);
        f32x2 f;
        f.x = bflo(q0.x); f.y = bfhi(q0.x); a0 += w0 * f;
        f.x = bflo(q0.y); f.y = bfhi(q0.y); a1 += w0 * f;
        f.x = bflo(q0.z); f.y = bfhi(q0.z); a2 += w0 * f;
        f.x = bflo(q0.w); f.y = bfhi(q0.w); a3 += w0 * f;
        f.x = bflo(q1.x); f.y = bfhi(q1.x); a0 += w1 * f;
        f.x = bflo(q1.y); f.y = bfhi(q1.y); a1 += w1 * f;
        f.x = bflo(q1.z); f.y = bfhi(q1.z); a2 += w1 * f;
        f.x = bflo(q1.w); f.y = bfhi(q1.w); a3 += w1 * f;
        f.x = bflo(q2.x); f.y = bfhi(q2.x); a0 += w2 * f;
        f.x = bflo(q2.y); f.y = bfhi(q2.y); a1 += w2 * f;
        f.x = bflo(q2.z); f.y = bfhi(q2.z); a2 += w2 * f;
        f.x = bflo(q2.w); f.y = bfhi(q2.w); a3 += w2 * f;
        f.x = bflo(q3.x); f.y = bfhi(q3.x); a0 += w3 * f;
        f.x = bflo(q3.y); f.y = bfhi(q3.y); a1 += w3 * f;
        f.x = bflo(q3.z); f.y = bfhi(q3.z); a2 += w3 * f;
        f.x = bflo(q3.w); f.y = bfhi(q3.w); a3 += w3 * f;
    }
    for (; j + 4 < end; j += 8) {
        int sn0 = csr_src[j], sn1 = csr_src[j + 4];
        float t0 = el[sn0] + erd, t1 = el[sn1] + erd;
        uint4 q0 = *(const uint4*)(fb + ((unsigned)sn0 << 8));
        uint4 q1 = *(const uint4*)(fb + ((unsigned)sn1 << 8));
        t0 = fmaxf(t0, 0.2f * t0); t1 = fmaxf(t1, 0.2f * t1);
        float w0 = __expf(t0 - M), w1 = __expf(t1 - M);
        s += w0 + w1;
        f32x2 f;
        f.x = bflo(q0.x); f.y = bfhi(q0.x); a0 += w0 * f;
        f.x = bflo(q0.y); f.y = bfhi(q0.y); a1 += w0 * f;
        f.x = bflo(q0.z); f.y = bfhi(q0.z); a2 += w0 * f;
        f.x = bflo(q0.w); f.y = bfhi(q0.w); a3 += w0 * f;
        f.x = bflo(q1.x); f.y = bfhi(q1.x); a0 += w1 * f;
        f.x = bflo(q1.y); f.y = bfhi(q1.y); a1 += w1 * f;
        f.x = bflo(q1.z); f.y = bfhi(q1.z); a2 += w1 * f;
        f.x = bflo(q1.w); f.y = bfhi(q1.w); a3 += w1 * f;
    }
    if (j < end) {
        int sn = csr_src[j];
        float t = el[sn] + erd;
        uint4 q = *(const uint4*)(fb + ((unsigned)sn << 8));
        t = fmaxf(t, 0.2f * t);
        float w = __expf(t - M);
        s += w;
        f32x2 f;
        f.x = bflo(q.x); f.y = bfhi(q.x); a0 += w * f;
        f.x = bflo(q.y); f.y = bfhi(q.y); a1 += w * f;
        f.x = bflo(q.z); f.y = bfhi(q.z); a2 += w * f;
        f.x = bflo(q.w); f.y = bfhi(q.w); a3 += w * f;
    }
    float vr[8] = {a0.x, a0.y, a1.x, a1.y, a2.x, a2.y, a3.x, a3.y};
    #pragma unroll
    for (int c = 0; c < 8; ++c) {
        vr[c] += __shfl_xor(vr[c], 16);
        vr[c] += __shfl_xor(vr[c], 32);
    }
    s += __shfl_xor(s, 16);
    s += __shfl_xor(s, 32);
    float inv = (end > beg) ? 1.f / s : 0.f;
    if (lane < 16) {
        float4 b0 = ((const float4*)bias)[lane * 2];
        float4 b1 = ((const float4*)bias)[lane * 2 + 1];
        float v[8];
        v[0] = fmaxf(vr[0] * inv + b0.x, 0.f);
        v[1] = fmaxf(vr[1] * inv + b0.y, 0.f);
        v[2] = fmaxf(vr[2] * inv + b0.z, 0.f);
        v[3] = fmaxf(vr[3] * inv + b0.w, 0.f);
        v[4] = fmaxf(vr[4] * inv + b1.x, 0.f);
        v[5] = fmaxf(vr[5] * inv + b1.y, 0.f);
        v[6] = fmaxf(vr[6] * inv + b1.z, 0.f);
        v[7] = fmaxf(vr[7] * inv + b1.w, 0.f);
        uint4 pk;
        pk.x = bf16rne(v[0]) | (bf16rne(v[1]) << 16);
        pk.y = bf16rne(v[2]) | (bf16rne(v[3]) << 16);
        pk.z = bf16rne(v[4]) | (bf16rne(v[5]) << 16);
        pk.w = bf16rne(v[6]) | (bf16rne(v[7]) << 16);
        ((uint4*)outv)[(size_t)wid * 16 + lane] = pk;
    }
}

// ---------------- pooling ----------------

__global__ __launch_bounds__(256) void k_pool_partial(const unsigned short* __restrict__ x,
                                                      const int* __restrict__ gs,
                                                      const int* __restrict__ ge,
                                                      float* __restrict__ hg) {
    int g = blockIdx.x, c = blockIdx.y;
    int start = gs[g], last = ge[g];
    if (start > last) return;
    int sub = threadIdx.x & 15;
    int r   = threadIdx.x >> 4;
    const uint4* x4 = (const uint4*)x;
    float acc[8] = {};
    for (int n = start + c * 16 + r; n <= last; n += PCHUNK * 16) {
        uint4 q = x4[(size_t)n * 16 + sub];
        acc[0] += bflo(q.x); acc[1] += bfhi(q.x);
        acc[2] += bflo(q.y); acc[3] += bfhi(q.y);
        acc[4] += bflo(q.z); acc[5] += bfhi(q.z);
        acc[6] += bflo(q.w); acc[7] += bfhi(q.w);
    }
    __shared__ float sm[256][8];
    #pragma unroll
    for (int k = 0; k < 8; ++k) sm[threadIdx.x][k] = acc[k];
    __syncthreads();
    for (int off = 8; off >= 1; off >>= 1) {
        if (r < off) {
            #pragma unroll
            for (int k = 0; k < 8; ++k)
                sm[threadIdx.x][k] += sm[threadIdx.x + off * 16][k];
        }
        __syncthreads();
    }
    if (r == 0) {
        #pragma unroll
        for (int k = 0; k < 8; ++k)
            atomicAdd(&hg[g * D + sub * 8 + k], sm[sub][k]);
    }
}

__global__ void k_final(const float* __restrict__ hg, const int* __restrict__ gs,
                        const int* __restrict__ ge, const float* __restrict__ Wfc,
                        const float* __restrict__ bfc, float* __restrict__ out) {
    int g = threadIdx.x;
    if (g >= NUM_GRAPHS) return;
    int start = gs[g], last = ge[g];
    float cnt = (start <= last) ? (float)(last - start + 1) : 1.f;
    float ic = 1.f / cnt;
    float l0 = bfc[0], l1 = bfc[1];
    for (int d = 0; d < D; d++) {
        float v = hg[g * D + d] * ic;
        l0 += v * Wfc[2 * d];
        l1 += v * Wfc[2 * d + 1];
    }
    float mm = fmaxf(l0, l1);
    float lse = mm + logf(expf(l0 - mm) + expf(l1 - mm));
    out[2 * g] = l0 - lse;
    out[2 * g + 1] = l1 - lse;
}

// ---------------- launch ----------------

extern "C" void kernel_launch(void* const* d_in, const int* in_sizes, int n_in,
                              void* d_out, int out_size, void* d_ws, size_t ws_size,
                              hipStream_t stream) {
    const float* h   = (const float*)d_in[0];
    const int* src   = (const int*)d_in[1];
    const int* dst   = (const int*)d_in[2];
    const int* gid   = (const int*)d_in[3];
    const float* W1  = (const float*)d_in[4];
    const float* al1 = (const float*)d_in[5];
    const float* ar1 = (const float*)d_in[6];
    const float* b1  = (const float*)d_in[7];
    const float* W2  = (const float*)d_in[8];
    const float* al2 = (const float*)d_in[9];
    const float* ar2 = (const float*)d_in[10];
    const float* b2  = (const float*)d_in[11];
    const float* Wfc = (const float*)d_in[12];
    const float* bfc = (const float*)d_in[13];
    float* out = (float*)d_out;

    int N = in_sizes[0] / D;
    int E = in_sizes[1];
    int NB = (N + 127) >> 7;

    char* p = (char*)d_ws;
    unsigned short* feat16  = (unsigned short*)p; p += (size_t)N * D * 2;  // GEMM out
    unsigned short* featAgg = (unsigned short*)p; p += (size_t)N * D * 2;  // agg out (bf16)
    float* el    = (float*)p; p += (size_t)N * 4;
    float* er    = (float*)p; p += (size_t)N * 4;
    int* row_ptr = (int*)p;   p += (size_t)(N + 4) * 4;
    int* csr_src = (int*)p;   p += (size_t)E * 4;
    unsigned* part = (unsigned*)p; p += (size_t)E * 4;
    // zero-region: bhist + glmax + hg (one memset)
    int* bhist   = (int*)p;   p += 1028 * 4;
    unsigned* glmaxu = (unsigned*)p; p += 4 * 4;
    float* hg    = (float*)p; p += NUM_GRAPHS * D * 4;
    size_t zbytes = (char*)p - (char*)bhist;
    int* bbase   = (int*)p;   p += 1028 * 4;
    int* bcur    = (int*)p;   p += 1028 * 4;
    int* gs      = (int*)p;   p += NUM_GRAPHS * 4;
    int* ge      = (int*)p;   p += NUM_GRAPHS * 4;
    unsigned short* Wt1 = (unsigned short*)p; p += D * D * 2;
    unsigned short* Wt2 = (unsigned short*)p; p += D * D * 2;

    int nbN = (N + 255) / 256;
    int nbW = (N * 64 + 255) / 256;
    int nbT = (E + ETILE - 1) / ETILE;
    int gemmB = (N + MT - 1) / MT;

    hipMemsetAsync(bhist, 0, zbytes, stream);                // bhist + glmax + hg
    hipMemsetAsync(gs, 0x7f, NUM_GRAPHS * 4, stream);
    hipMemsetAsync(ge, 0xff, NUM_GRAPHS * 4, stream);

    // front: bucket histogram + weight transpose + graph bounds (one kernel)
    k_front<<<nbT + 16 + nbN, 256, 0, stream>>>(dst, bhist, E, nbT,
                                                W1, W2, Wt1, Wt2, gid, gs, ge, N);
    k_bucket_scan<<<1, 1024, 0, stream>>>(bhist, bbase, bcur, NB, E, row_ptr, N);
    k_partition<<<nbT, 256, 0, stream>>>(src, dst, bcur, part, E);

    // Layer 1: MFMA GEMM (fp32 in) + el/er + glmax, overlapped with bucket->CSR
    k_gemm_mfma_sort<<<gemmB + NB, 256, 0, stream>>>(
        h, 1, Wt1, al1, ar1, feat16, el, er, glmaxu, N, gemmB,
        part, bbase, row_ptr, csr_src);
    k_aggregate<<<nbW, 256, 0, stream>>>(feat16, el, er, row_ptr, csr_src,
                                         b1, glmaxu, featAgg, N);

    // Layer 2: MFMA GEMM (bf16 in), all blocks gemm role
    k_gemm_mfma_sort<<<gemmB, 256, 0, stream>>>(
        featAgg, 0, Wt2, al2, ar2, feat16, el, er, glmaxu + 1, N, gemmB,
        part, bbase, row_ptr, csr_src);
    k_aggregate<<<nbW, 256, 0, stream>>>(feat16, el, er, row_ptr, csr_src,
                                         b2, glmaxu + 1, featAgg, N);

    // Pool + FC + log_softmax
    k_pool_partial<<<dim3(NUM_GRAPHS, PCHUNK), 256, 0, stream>>>(featAgg, gs, ge, hg);
    k_final<<<1, 64, 0, stream>>>(hg, gs, ge, Wfc, bfc, out);
}